// Round 6
// baseline (620.568 us; speedup 1.0000x reference)
//
#include <hip/hip_runtime.h>
#include <math.h>

typedef __bf16 bf16;
typedef bf16 bf16x8 __attribute__((ext_vector_type(8)));
typedef float f32x4 __attribute__((ext_vector_type(4)));
typedef unsigned int u32;

#define T_DIM 1024
#define H_DIM 1024
#define E_NUM 64
#define I_DIM 512
#define KTOP 6
#define TKG 3
#define CAP 256
#define A_TOT (T_DIM * KTOP)
#define SCALE_F 2.5f

#define BMx 64
#define BNx 128
#define BKx 64            // k elems per tile
#define ABUF (BMx * BKx)  // 4096 elems = 8 KB per A buffer

// global_load_lds: per-lane global addr; LDS dest = wave-uniform base + lane*16.
typedef const u32 __attribute__((address_space(1)))* gas_t;
typedef u32 __attribute__((address_space(3)))* las_t;
__device__ __forceinline__ void gld16(const void* g, void* l) {
  __builtin_amdgcn_global_load_lds((gas_t)(unsigned long long)g,
                                   (las_t)(u32)(unsigned long long)l, 16, 0, 0);
}

// B-LDS swizzle: chunk stored at (kc ^ s(n)); conflict-free b128 writes, 2-way reads.
__device__ __forceinline__ int bswz(int n) {
  return ((n >> 2) ^ ((n & 3) << 1)) & 7;
}

// ---------------------------------------------------------------- convert x -> bf16
__global__ __launch_bounds__(256) void cvt_bf16(const float* __restrict__ in,
                                                bf16* __restrict__ out) {
  int i = (blockIdx.x * 256 + threadIdx.x) * 4;
  float4 v = *(const float4*)(in + i);
  bf16 __align__(8) t[4] = {(bf16)v.x, (bf16)v.y, (bf16)v.z, (bf16)v.w};
  *(uint2*)(out + i) = *(const uint2*)t;
}

// ---------------------------------------------------------------- router + grouped top-k
__global__ __launch_bounds__(256) void router_topk(const float* __restrict__ x,
                                                   const float* __restrict__ gw,
                                                   const float* __restrict__ bias,
                                                   int* __restrict__ topk_id,
                                                   float* __restrict__ topk_w) {
  __shared__ float part[4][64];
  const int t = blockIdx.x;
  const int tid = threadIdx.x;
  const int wave = tid >> 6, lane = tid & 63;
  const float* xr = x + (long)t * H_DIM + wave * 256;
  float acc = 0.f;
  for (int h = 0; h < 256; h += 4) {
    float4 xv = *(const float4*)(xr + h);
    int hh = wave * 256 + h;
    acc += xv.x * gw[(hh + 0) * E_NUM + lane];
    acc += xv.y * gw[(hh + 1) * E_NUM + lane];
    acc += xv.z * gw[(hh + 2) * E_NUM + lane];
    acc += xv.w * gw[(hh + 3) * E_NUM + lane];
  }
  part[wave][lane] = acc;
  __syncthreads();
  if (wave != 0) return;
  acc = part[0][lane] + part[1][lane] + part[2][lane] + part[3][lane];

  float score = 1.f / (1.f + __expf(-acc));  // sigmoid (weights come from this)
  float sel = score + bias[lane];            // biased score (selection only)

  // top-2 within each group of 8 lanes
  float m1 = sel, m2 = -INFINITY;
  #pragma unroll
  for (int off = 1; off < 8; off <<= 1) {
    float o1 = __shfl_xor(m1, off);
    float o2 = __shfl_xor(m2, off);
    float mn = fminf(m1, o1);
    float alt = (m1 >= o1) ? m2 : o2;
    m1 = fmaxf(m1, o1);
    m2 = fmaxf(mn, alt);
  }
  float gscore = m1 + m2;

  // top-3 groups (argmax, lowest-index tiebreak)
  const int my_g = lane >> 3;
  unsigned gmask = 0;
  float gv = ((lane & 7) == 0) ? gscore : -INFINITY;
  for (int r = 0; r < TKG; ++r) {
    float v = gv;
    int idx = my_g;
    #pragma unroll
    for (int off = 1; off < 64; off <<= 1) {
      float ov = __shfl_xor(v, off);
      int oi = __shfl_xor(idx, off);
      if (ov > v || (ov == v && oi < idx)) { v = ov; idx = oi; }
    }
    gmask |= 1u << idx;
    if (my_g == idx) gv = -INFINITY;
  }

  // top-6 experts within selected groups
  float cand = ((gmask >> my_g) & 1u) ? sel : -INFINITY;
  float wk[KTOP];
  int ik[KTOP];
  float wsum = 0.f;
  for (int r = 0; r < KTOP; ++r) {
    float v = cand;
    int idx = lane;
    #pragma unroll
    for (int off = 1; off < 64; off <<= 1) {
      float ov = __shfl_xor(v, off);
      int oi = __shfl_xor(idx, off);
      if (ov > v || (ov == v && oi < idx)) { v = ov; idx = oi; }
    }
    float w = __shfl(score, idx);  // weight from UN-biased score
    wk[r] = w; ik[r] = idx; wsum += w;
    if (lane == idx) cand = -INFINITY;
  }
  if (lane == 0) {
    float inv = 1.f / wsum;
    #pragma unroll
    for (int r = 0; r < KTOP; ++r) {
      topk_id[t * KTOP + r] = ik[r];
      topk_w[t * KTOP + r] = wk[r] * inv;
    }
  }
}

// ---------------------------------------------------------------- dispatch (ordered compaction)
__global__ __launch_bounds__(64) void dispatch(const int* __restrict__ topk_id,
                                               int* __restrict__ rowlist,
                                               int* __restrict__ slot_a,
                                               int* __restrict__ counts) {
  __shared__ int ids[A_TOT];
  const int e = blockIdx.x, lane = threadIdx.x;
  for (int i = lane; i < A_TOT; i += 64) ids[i] = topk_id[i];
  __syncthreads();
  int base = 0;
  for (int a0 = 0; a0 < A_TOT; a0 += 64) {
    int a = a0 + lane;
    bool m = (ids[a] == e);
    unsigned long long bal = __ballot(m);
    if (m) {
      int pos = base + __popcll(bal & ((1ull << lane) - 1ull));
      slot_a[a] = (pos < CAP) ? pos : -1;
      if (pos < CAP) rowlist[e * CAP + pos] = a;
    }
    base += __popcll(bal);
  }
  if (lane == 0) counts[e] = (base < CAP) ? base : CAP;
}

// ================================================================ 64x128 MFMA GEMM, pipelined:
// loads for tile k+1 issue AFTER barrier1 so the pre-barrier2 vmcnt(0) drain has
// MFMA cover; cross-block TLP (~4 blocks/CU) hides the residual.

// ---------------------------------------------------------------- gate_up + fused SiLU*mul
__global__ __launch_bounds__(256) void gemm_gu(
    const bf16* __restrict__ X, int x_ld,
    const int* __restrict__ rows, const int* __restrict__ counts, int n_rows_fixed,
    const float* __restrict__ W, long w_estride, int ldb, int u_off,
    bf16* __restrict__ act, int act_ld, long act_estride, int kdim) {
  __shared__ union {
    struct { bf16 A[2 * ABUF]; bf16 B[BNx * BKx]; } st;  // 16 KB + 16 KB
    bf16 epi[BMx * 72];                                   // 9.2 KB repack
  } sm;
  const int e = blockIdx.z;
  const int n_rows = counts ? counts[e] : n_rows_fixed;
  const int m0 = blockIdx.x * BMx;
  if (m0 >= n_rows) return;
  const int nb = blockIdx.y;
  const int tid = threadIdx.x;
  const int w = tid >> 6, lane = tid & 63;
  const int q = lane >> 4, l16 = lane & 15;
  const int m_off = (w & 1) * 32;

  // ---- A staging geometry (global_load_lds): wave w covers rows w*16..w*16+15 (2 insts)
  const int srow = w * 16 + (lane >> 3);
  const int gchunk = (lane & 7) ^ (lane >> 3);
  const bf16* pA[2];
  #pragma unroll
  for (int j = 0; j < 2; ++j) {
    int tr = m0 + srow + j * 8;
    int grow;
    if (rows) grow = (tr < n_rows) ? (rows[e * CAP + tr] / KTOP) : 0;
    else grow = tr;
    pA[j] = X + (long)grow * x_ld + gchunk * 8;
  }
  bf16* ldsA = sm.st.A + w * 1024 + lane * 8;

  // ---- B staging geometry (fp32 -> regs -> bf16 LDS transposed)
  const int kc = tid >> 5;          // 0..7 (k-chunk of 8 rows)
  const int n0 = (tid & 31) * 4;    // local col base 0..124
  const int gcol = (n0 < 64) ? (nb * 64 + n0) : (u_off + nb * 64 + (n0 - 64));
  const float* bcol = W + (long)e * w_estride + (long)kc * 8 * ldb + gcol;
  float4 bv[8];
  #pragma unroll
  for (int r = 0; r < 8; ++r) bv[r] = *(const float4*)(bcol + (long)r * ldb);

  // prologue: A(0) into buffer 0
  #pragma unroll
  for (int j = 0; j < 2; ++j) {
    gld16(pA[j], ldsA + j * 512);
    pA[j] += BKx;
  }

  f32x4 acc[2][4];
  #pragma unroll
  for (int i = 0; i < 2; ++i)
    #pragma unroll
    for (int j = 0; j < 4; ++j) acc[i][j] = (f32x4){0.f, 0.f, 0.f, 0.f};

  const int niter = kdim / BKx;
  for (int k = 0; k < niter; ++k) {
    const int p = k & 1;
    // stage B(k): regs -> LDS (4x ds_write_b128)
    #pragma unroll
    for (int j = 0; j < 4; ++j) {
      bf16 __align__(16) t8[8];
      #pragma unroll
      for (int r = 0; r < 8; ++r) t8[r] = (bf16)((const float*)&bv[r])[j];
      int n = n0 + j;
      *(uint4*)(sm.st.B + n * BKx + ((kc ^ bswz(n)) * 8)) = *(const uint4*)t8;
    }
    __syncthreads();  // drains ds_writes (+ prologue gld16 on k=0)

    // issue next-tile loads NOW: drained at the post-MFMA barrier (covered)
    if (k + 1 < niter) {
      const float* bnext = bcol + (long)(k + 1) * BKx * ldb;
      #pragma unroll
      for (int r = 0; r < 8; ++r) bv[r] = *(const float4*)(bnext + (long)r * ldb);
      #pragma unroll
      for (int j = 0; j < 2; ++j) {
        gld16(pA[j], ldsA + (1 - p) * ABUF + j * 512);
        pA[j] += BKx;
      }
    }

    #pragma unroll
    for (int kh = 0; kh < 2; ++kh) {
      bf16x8 a[2], b[4];
      const int co = ((kh * 4 + q) ^ (l16 & 7)) * 8;
      #pragma unroll
      for (int i = 0; i < 2; ++i)
        a[i] = *(const bf16x8*)(sm.st.A + p * ABUF + (m_off + i * 16 + l16) * BKx + co);
      #pragma unroll
      for (int j = 0; j < 4; ++j) {
        int nf = (j >> 1) * 64 + (w >> 1) * 32 + (j & 1) * 16;  // gate: j<2; up: j>=2
        int n = nf + l16;
        b[j] = *(const bf16x8*)(sm.st.B + n * BKx + (((kh * 4 + q) ^ bswz(n)) * 8));
      }
      #pragma unroll
      for (int i = 0; i < 2; ++i)
        #pragma unroll
        for (int j = 0; j < 4; ++j)
          acc[i][j] = __builtin_amdgcn_mfma_f32_16x16x32_bf16(a[i], b[j], acc[i][j], 0, 0, 0);
    }
    __syncthreads();  // drains next-tile gld16 + bv loads, covered by MFMAs
  }

  // SiLU(g)*u in registers: g=acc[i][j], u=acc[i][j+2] (same row, col+64)
  const int c_base = (w >> 1) * 32;
  #pragma unroll
  for (int i = 0; i < 2; ++i)
    #pragma unroll
    for (int j = 0; j < 2; ++j)
      #pragma unroll
      for (int r = 0; r < 4; ++r) {
        float g = acc[i][j][r], uu = acc[i][j + 2][r];
        float s = g / (1.f + __expf(-g));
        sm.epi[(m_off + i * 16 + q * 4 + r) * 72 + c_base + j * 16 + l16] = (bf16)(s * uu);
      }
  __syncthreads();
  #pragma unroll
  for (int p = 0; p < 2; ++p) {
    int row = p * 32 + (tid >> 3);
    int c0 = (tid & 7) * 8;
    uint4 v = *(const uint4*)(sm.epi + row * 72 + c0);
    *(uint4*)(act + (long)e * act_estride + (long)(m0 + row) * act_ld + nb * 64 + c0) = v;
  }
}

// ---------------------------------------------------------------- down GEMM
template <typename OutT>
__global__ __launch_bounds__(256) void gemm_dn(
    const bf16* __restrict__ Abase, long a_estride, int a_ld,
    const int* __restrict__ rowsO, const int* __restrict__ counts, int n_rows_fixed,
    const float* __restrict__ W, long w_estride, int ldb,
    OutT* __restrict__ Out, int out_ld, int kdim) {
  __shared__ union {
    struct { bf16 A[2 * ABUF]; bf16 B[BNx * BKx]; } st;  // 32 KB
    bf16 epi[BMx * 136];  // 17.4 KB bf16 repack
  } sm;
  const int e = blockIdx.z;
  const int n_rows = counts ? counts[e] : n_rows_fixed;
  const int m0 = blockIdx.x * BMx;
  if (m0 >= n_rows) return;
  const int nb = blockIdx.y;
  const int tid = threadIdx.x;
  const int w = tid >> 6, lane = tid & 63;
  const int q = lane >> 4, l16 = lane & 15;
  const int m_off = (w & 1) * 32;
  const int n_off = (w >> 1) * 64;

  const int srow = w * 16 + (lane >> 3);
  const int gchunk = (lane & 7) ^ (lane >> 3);
  const bf16* pA[2];
  #pragma unroll
  for (int j = 0; j < 2; ++j)
    pA[j] = Abase + (long)e * a_estride + (long)(m0 + srow + j * 8) * a_ld + gchunk * 8;
  bf16* ldsA = sm.st.A + w * 1024 + lane * 8;

  const int kc = tid >> 5;
  const int n0 = (tid & 31) * 4;
  const float* bcol = W + (long)e * w_estride + (long)kc * 8 * ldb + nb * BNx + n0;
  float4 bv[8];
  #pragma unroll
  for (int r = 0; r < 8; ++r) bv[r] = *(const float4*)(bcol + (long)r * ldb);

  #pragma unroll
  for (int j = 0; j < 2; ++j) {
    gld16(pA[j], ldsA + j * 512);
    pA[j] += BKx;
  }

  f32x4 acc[2][4];
  #pragma unroll
  for (int i = 0; i < 2; ++i)
    #pragma unroll
    for (int j = 0; j < 4; ++j) acc[i][j] = (f32x4){0.f, 0.f, 0.f, 0.f};

  const int niter = kdim / BKx;
  for (int k = 0; k < niter; ++k) {
    const int p = k & 1;
    #pragma unroll
    for (int j = 0; j < 4; ++j) {
      bf16 __align__(16) t8[8];
      #pragma unroll
      for (int r = 0; r < 8; ++r) t8[r] = (bf16)((const float*)&bv[r])[j];
      int n = n0 + j;
      *(uint4*)(sm.st.B + n * BKx + ((kc ^ bswz(n)) * 8)) = *(const uint4*)t8;
    }
    __syncthreads();

    if (k + 1 < niter) {
      const float* bnext = bcol + (long)(k + 1) * BKx * ldb;
      #pragma unroll
      for (int r = 0; r < 8; ++r) bv[r] = *(const float4*)(bnext + (long)r * ldb);
      #pragma unroll
      for (int j = 0; j < 2; ++j) {
        gld16(pA[j], ldsA + (1 - p) * ABUF + j * 512);
        pA[j] += BKx;
      }
    }

    #pragma unroll
    for (int kh = 0; kh < 2; ++kh) {
      bf16x8 a[2], b[4];
      const int co = ((kh * 4 + q) ^ (l16 & 7)) * 8;
      #pragma unroll
      for (int i = 0; i < 2; ++i)
        a[i] = *(const bf16x8*)(sm.st.A + p * ABUF + (m_off + i * 16 + l16) * BKx + co);
      #pragma unroll
      for (int j = 0; j < 4; ++j) {
        int n = n_off + j * 16 + l16;
        b[j] = *(const bf16x8*)(sm.st.B + n * BKx + (((kh * 4 + q) ^ bswz(n)) * 8));
      }
      #pragma unroll
      for (int i = 0; i < 2; ++i)
        #pragma unroll
        for (int j = 0; j < 4; ++j)
          acc[i][j] = __builtin_amdgcn_mfma_f32_16x16x32_bf16(a[i], b[j], acc[i][j], 0, 0, 0);
    }
    __syncthreads();
  }

  if constexpr (sizeof(OutT) == 4) {
    #pragma unroll
    for (int i = 0; i < 2; ++i)
      #pragma unroll
      for (int j = 0; j < 4; ++j)
        #pragma unroll
        for (int r = 0; r < 4; ++r) {
          int row = m0 + m_off + i * 16 + q * 4 + r;
          Out[(long)row * out_ld + nb * BNx + n_off + j * 16 + l16] = acc[i][j][r];
        }
  } else {
    #pragma unroll
    for (int i = 0; i < 2; ++i)
      #pragma unroll
      for (int j = 0; j < 4; ++j)
        #pragma unroll
        for (int r = 0; r < 4; ++r)
          sm.epi[(m_off + i * 16 + q * 4 + r) * 136 + n_off + j * 16 + l16] = (bf16)acc[i][j][r];
    __syncthreads();
    #pragma unroll
    for (int p = 0; p < 4; ++p) {
      int row = p * 16 + (tid >> 4);
      int c0 = (tid & 15) * 8;
      if (m0 + row < n_rows) {
        long orow = rowsO ? (long)rowsO[e * CAP + m0 + row] : (long)(m0 + row);
        *(uint4*)((bf16*)Out + orow * out_ld + nb * BNx + c0) =
            *(const uint4*)(sm.epi + row * 136 + c0);
      }
    }
  }
}

// ---------------------------------------------------------------- combine
__global__ __launch_bounds__(256) void combine(const float* __restrict__ tkw,
                                               const int* __restrict__ slot_a,
                                               const bf16* __restrict__ Ya,
                                               float* __restrict__ out) {
  const int t = blockIdx.x, tid = threadIdx.x;
  long o = (long)t * H_DIM + tid * 4;
  float4 v = *(float4*)(out + o);  // shared-expert result already here
  float a0 = v.x, a1 = v.y, a2 = v.z, a3 = v.w;
  #pragma unroll
  for (int k = 0; k < KTOP; ++k) {
    int a = t * KTOP + k;
    if (slot_a[a] >= 0) {
      float w = tkw[a] * SCALE_F;
      const bf16* yr = Ya + (long)a * H_DIM + tid * 4;
      uint2 yv = *(const uint2*)yr;
      bf16 __align__(8) yb[4];
      *(uint2*)yb = yv;
      a0 += w * (float)yb[0];
      a1 += w * (float)yb[1];
      a2 += w * (float)yb[2];
      a3 += w * (float)yb[3];
    }
  }
  *(float4*)(out + o) = make_float4(a0, a1, a2, a3);
}

// ---------------------------------------------------------------- launch
extern "C" void kernel_launch(void* const* d_in, const int* in_sizes, int n_in,
                              void* d_out, int out_size, void* d_ws, size_t ws_size,
                              hipStream_t stream) {
  const float* x     = (const float*)d_in[0];
  const float* gw    = (const float*)d_in[1];
  const float* bias  = (const float*)d_in[2];
  const float* w_gu  = (const float*)d_in[3];
  const float* w_dn  = (const float*)d_in[4];
  const float* ws_gu = (const float*)d_in[5];
  const float* ws_dn = (const float*)d_in[6];
  float* out = (float*)d_out;
  char* ws = (char*)d_ws;

  // workspace layout (bytes), total ~34 MB
  bf16* xbf     = (bf16*)(ws + 0);           //  2,097,152
  bf16* acts    = (bf16*)(ws + 2097152);     //  2,097,152  shared act [T][1024]
  bf16* actr    = (bf16*)(ws + 4194304);     // 16,777,216  routed act [E][CAP][512]
  bf16* Ya      = (bf16*)(ws + 20971520);    // 12,582,912  routed out [A_TOT][1024]
  int*  tki     = (int*)(ws + 33554432);     // 24,576
  float* tkw    = (float*)(ws + 33579008);   // 24,576
  int*  rowlist = (int*)(ws + 33603584);     // 65,536
  int*  slot_a  = (int*)(ws + 33669120);     // 24,576
  int*  counts  = (int*)(ws + 33693696);     // 1,024

  cvt_bf16<<<dim3((T_DIM * H_DIM) / 1024), dim3(256), 0, stream>>>(x, xbf);
  router_topk<<<dim3(T_DIM), dim3(256), 0, stream>>>(x, gw, bias, tki, tkw);
  dispatch<<<dim3(E_NUM), dim3(64), 0, stream>>>(tki, rowlist, slot_a, counts);

  // routed gate_up + silu: B = w_gu [e][1024][1024] fp32, gate cols 0..511, up 512..1023
  gemm_gu<<<dim3(CAP / BMx, I_DIM / 64, E_NUM), dim3(256), 0, stream>>>(
      xbf, H_DIM, rowlist, counts, 0,
      w_gu, (long)H_DIM * 2 * I_DIM, 2 * I_DIM, I_DIM,
      actr, I_DIM, (long)CAP * I_DIM, H_DIM);

  // shared gate_up + silu: B = ws_gu [1024][2048] fp32, u_off 1024
  gemm_gu<<<dim3(T_DIM / BMx, 1024 / 64, 1), dim3(256), 0, stream>>>(
      xbf, H_DIM, nullptr, nullptr, T_DIM,
      ws_gu, 0, 2048, 1024,
      acts, 1024, 0, H_DIM);

  // routed down -> Ya (gathered rows): B = w_dn [e][512][1024] fp32
  gemm_dn<bf16><<<dim3(CAP / BMx, H_DIM / BNx, E_NUM), dim3(256), 0, stream>>>(
      actr, (long)CAP * I_DIM, I_DIM, rowlist, counts, 0,
      w_dn, (long)I_DIM * H_DIM, H_DIM,
      (bf16*)Ya, H_DIM, I_DIM);

  // shared down -> out fp32 (full overwrite): B = ws_dn [1024][1024] fp32
  gemm_dn<float><<<dim3(T_DIM / BMx, H_DIM / BNx, 1), dim3(256), 0, stream>>>(
      acts, 0, 1024, nullptr, nullptr, T_DIM,
      ws_dn, 0, H_DIM,
      out, H_DIM, 1024);

  combine<<<dim3(T_DIM), dim3(256), 0, stream>>>(tkw, slot_a, Ya, out);
}